// Round 2
// baseline (599.343 us; speedup 1.0000x reference)
//
#include <hip/hip_runtime.h>
#include <hip/hip_bf16.h>
#include <cstdint>
#include <cstddef>

typedef __bf16 bf16_t;
typedef __attribute__((ext_vector_type(8))) __bf16 bf16x8;
typedef __attribute__((ext_vector_type(4))) __bf16 bf16x4;
typedef __attribute__((ext_vector_type(4))) float floatx4;

#define BM 128
#define BN 128
#define BK 32

// ---------------------------------------------------------------- helpers
__device__ __forceinline__ void async_copy_16B(const void* g, void* l) {
  __builtin_amdgcn_global_load_lds(
      (const __attribute__((address_space(1))) void*)g,
      (__attribute__((address_space(3))) void*)l, 16, 0, 0);
}

// ---------------------------------------------------------------- casts
__global__ __launch_bounds__(256) void cast_f32_to_bf16(
    const float* __restrict__ in, bf16_t* __restrict__ out, int n) {
  const int i = (blockIdx.x * 256 + threadIdx.x) * 4;
  if (i >= n) return;
  const float4 v = *(const float4*)(in + i);
  bf16x4 o;
  o.x = (bf16_t)v.x; o.y = (bf16_t)v.y; o.z = (bf16_t)v.z; o.w = (bf16_t)v.w;
  *(bf16x4*)(out + i) = o;
}

// w_dw [4096][127] -> wt [127][4096]
__global__ __launch_bounds__(256) void transpose_w(
    const float* __restrict__ w, float* __restrict__ wt) {
  const int idx = blockIdx.x * 256 + threadIdx.x;
  if (idx >= 127 * 4096) return;
  const int j = idx >> 12;
  const int c = idx & 4095;
  wt[idx] = w[c * 127 + j];
}

// ---------------------------------------------------------------- GEMM (NT)
// C[M,N] = A[M,K] * B[N,K]^T ; A,B bf16 row-major, C = OutT row-major.
// 128x128 tile, BK=32, 4 waves each computing 64x64 via 4x4 mfma_16x16x32.
template <typename OutT>
__global__ __launch_bounds__(256) void gemm_bt(
    const bf16_t* __restrict__ A, const bf16_t* __restrict__ B,
    OutT* __restrict__ C, int M, int N, int K) {
  __shared__ bf16_t As[BM * BK];
  __shared__ bf16_t Bs[BN * BK];
  const int t = threadIdx.x;
  const int lane = t & 63;
  const int wave = t >> 6;
  const int m0 = blockIdx.y * BM;
  const int n0 = blockIdx.x * BN;
  const int wr = (wave >> 1) * 64;
  const int wc = (wave & 1) * 64;
  const int fr = lane & 15;
  const int fk = (lane >> 4) * 8;

  floatx4 acc[4][4] = {};

  const int kTiles = K / BK;
  for (int kt = 0; kt < kTiles; ++kt) {
    const int k0 = kt * BK;
    __syncthreads();
#pragma unroll
    for (int it = 0; it < 2; ++it) {
      const int chunk = it * 256 + t;
      const int row = chunk >> 2;
      const int kc = (chunk & 3) * 8;
      async_copy_16B(A + (size_t)(m0 + row) * K + k0 + kc, As + chunk * 8);
      async_copy_16B(B + (size_t)(n0 + row) * K + k0 + kc, Bs + chunk * 8);
    }
    __syncthreads();

    bf16x8 af[4], bfr[4];
#pragma unroll
    for (int i = 0; i < 4; ++i) {
      af[i]  = *(const bf16x8*)(As + (wr + i * 16 + fr) * BK + fk);
      bfr[i] = *(const bf16x8*)(Bs + (wc + i * 16 + fr) * BK + fk);
    }
#pragma unroll
    for (int i = 0; i < 4; ++i)
#pragma unroll
      for (int j = 0; j < 4; ++j)
        acc[i][j] = __builtin_amdgcn_mfma_f32_16x16x32_bf16(
            af[i], bfr[j], acc[i][j], 0, 0, 0);
  }

  const int cr = (lane >> 4) * 4;
  const int cc = lane & 15;
#pragma unroll
  for (int i = 0; i < 4; ++i)
#pragma unroll
    for (int j = 0; j < 4; ++j)
#pragma unroll
      for (int r = 0; r < 4; ++r) {
        const int row = m0 + wr + i * 16 + cr + r;
        const int col = n0 + wc + j * 16 + cc;
        C[(size_t)row * N + col] = (OutT)acc[i][j][r];
      }
}

// Split-K variant: blockIdx.z = split index z; reduces K-range [z*Ks,(z+1)*Ks)
// writes fp32 partial P[z][M][N].
__global__ __launch_bounds__(256) void gemm_bt_split(
    const bf16_t* __restrict__ A, const bf16_t* __restrict__ B,
    float* __restrict__ P, int M, int N, int K, int Ks) {
  __shared__ bf16_t As[BM * BK];
  __shared__ bf16_t Bs[BN * BK];
  const int z = blockIdx.z;
  A += (size_t)z * Ks;
  B += (size_t)z * Ks;
  P += (size_t)z * M * N;
  const int t = threadIdx.x;
  const int lane = t & 63;
  const int wave = t >> 6;
  const int m0 = blockIdx.y * BM;
  const int n0 = blockIdx.x * BN;
  const int wr = (wave >> 1) * 64;
  const int wc = (wave & 1) * 64;
  const int fr = lane & 15;
  const int fk = (lane >> 4) * 8;

  floatx4 acc[4][4] = {};

  const int kTiles = Ks / BK;
  for (int kt = 0; kt < kTiles; ++kt) {
    const int k0 = kt * BK;
    __syncthreads();
#pragma unroll
    for (int it = 0; it < 2; ++it) {
      const int chunk = it * 256 + t;
      const int row = chunk >> 2;
      const int kc = (chunk & 3) * 8;
      async_copy_16B(A + (size_t)(m0 + row) * K + k0 + kc, As + chunk * 8);
      async_copy_16B(B + (size_t)(n0 + row) * K + k0 + kc, Bs + chunk * 8);
    }
    __syncthreads();

    bf16x8 af[4], bfr[4];
#pragma unroll
    for (int i = 0; i < 4; ++i) {
      af[i]  = *(const bf16x8*)(As + (wr + i * 16 + fr) * BK + fk);
      bfr[i] = *(const bf16x8*)(Bs + (wc + i * 16 + fr) * BK + fk);
    }
#pragma unroll
    for (int i = 0; i < 4; ++i)
#pragma unroll
      for (int j = 0; j < 4; ++j)
        acc[i][j] = __builtin_amdgcn_mfma_f32_16x16x32_bf16(
            af[i], bfr[j], acc[i][j], 0, 0, 0);
  }

  const int cr = (lane >> 4) * 4;
  const int cc = lane & 15;
#pragma unroll
  for (int i = 0; i < 4; ++i)
#pragma unroll
    for (int j = 0; j < 4; ++j)
#pragma unroll
      for (int r = 0; r < 4; ++r) {
        const int row = m0 + wr + i * 16 + cr + r;
        const int col = n0 + wc + j * 16 + cc;
        P[(size_t)row * N + col] = acc[i][j][r];
      }
}

__global__ __launch_bounds__(256) void reduce2(
    const float* __restrict__ P, float* __restrict__ out, int n) {
  const int i = (blockIdx.x * 256 + threadIdx.x) * 4;
  if (i >= n) return;
  const float4 a = *(const float4*)(P + i);
  const float4 b = *(const float4*)(P + n + i);
  float4 r;
  r.x = a.x + b.x; r.y = a.y + b.y; r.z = a.z + b.z; r.w = a.w + b.w;
  *(float4*)(out + i) = r;
}

// ---------------------------------------------------------------- conv+gate
// vg: [8192][8192] bf16 (v = cols 0..4095, g = cols 4096..8191)
// wt: [127][4096] fp32 transposed filters ; y: [8192][4096] bf16
// Block: 64 channels x 128 l-outputs; 4 waves x 32 l's each, lane=channel.
#define CONV_L 128
#define CROWS 254  // 128 + 126 history rows

__global__ __launch_bounds__(256) void conv_gate(
    const bf16_t* __restrict__ vg, const float* __restrict__ wt,
    const float* __restrict__ b_dw, bf16_t* __restrict__ y) {
  __shared__ bf16_t vt[CROWS * 64];
  const int t = threadIdx.x;
  const int lane = t & 63;
  const int wave = t >> 6;
  const int c0 = blockIdx.x * 64;
  const int lt = blockIdx.y & 31;   // 4096/128 = 32 l-tiles
  const int b = blockIdx.y >> 5;
  const int l0 = lt * CONV_L;

  // stage v tile rows [l0-126, l0+127] x 64 channels (zeros for l<0)
  for (int chunk = t; chunk < CROWS * 8; chunk += 256) {
    const int row = chunk >> 3;
    const int cc = (chunk & 7) * 8;
    const int l = l0 - 126 + row;
    uint4* dst = (uint4*)(vt + row * 64 + cc);
    if (l < 0) {
      *dst = make_uint4(0u, 0u, 0u, 0u);
    } else {
      *dst = *(const uint4*)(vg + (size_t)(b * 4096 + l) * 8192 + c0 + cc);
    }
  }
  __syncthreads();

  const int c = c0 + lane;
  const int r0 = wave * 32;  // tile row of v[lb-126]
  const float bias = b_dw[c];
  float acc[32], win[32];
#pragma unroll
  for (int i = 0; i < 32; ++i) acc[i] = bias;
#pragma unroll
  for (int i = 0; i < 32; ++i) win[i] = (float)vt[(r0 + i) * 64 + lane];

  const float* wcp = wt + c;
  // invariant: at start of tap j, win[(j+i)&31] == v[r0+j+i], i in [0,32)
#pragma unroll 1
  for (int jo = 0; jo < 96; jo += 32) {
#pragma unroll
    for (int ji = 0; ji < 32; ++ji) {
      const int j = jo + ji;
      const float wj = wcp[(size_t)j * 4096];
#pragma unroll
      for (int i = 0; i < 32; ++i) acc[i] += wj * win[(ji + i) & 31];
      win[ji] = (float)vt[(r0 + 32 + j) * 64 + lane];
    }
  }
#pragma unroll
  for (int ji = 0; ji < 31; ++ji) {  // tail taps j = 96..126
    const int j = 96 + ji;
    const float wj = wcp[(size_t)j * 4096];
#pragma unroll
    for (int i = 0; i < 32; ++i) acc[i] += wj * win[(ji + i) & 31];
    if (ji < 30) win[ji] = (float)vt[(r0 + 32 + j) * 64 + lane];
  }

  const int lb = l0 + r0;
  const bf16_t* gp = vg + (size_t)(b * 4096 + lb) * 8192 + 4096 + c;
  bf16_t* yp = y + (size_t)(b * 4096 + lb) * 4096 + c;
#pragma unroll
  for (int i = 0; i < 32; ++i) {
    const float gv = (float)gp[(size_t)i * 8192];
    const float v = acc[i];
    const float sv = v / (1.f + __expf(-v));
    const float sg = gv / (1.f + __expf(-gv));
    yp[(size_t)i * 4096] = (bf16_t)(sv * sg);
  }
}

// ---------------------------------------------------------------- launch
extern "C" void kernel_launch(void* const* d_in, const int* in_sizes, int n_in,
                              void* d_out, int out_size, void* d_ws,
                              size_t ws_size, hipStream_t stream) {
  const float* x     = (const float*)d_in[0];  // [2,4096,1024]
  const float* w_in  = (const float*)d_in[1];  // [8192,1024]
  const float* w_dw  = (const float*)d_in[2];  // [4096,127]
  const float* b_dw  = (const float*)d_in[3];  // [4096]
  const float* w_out = (const float*)d_in[4];  // [1024,4096]
  float* out = (float*)d_out;                  // [2,4096,1024]

  char* p = (char*)d_ws;
  bf16_t* x_bf  = (bf16_t*)p; p += (size_t)8192 * 1024 * 2;
  bf16_t* wi_bf = (bf16_t*)p; p += (size_t)8192 * 1024 * 2;
  bf16_t* wo_bf = (bf16_t*)p; p += (size_t)1024 * 4096 * 2;
  float*  wt    = (float*)p;  p += (size_t)127 * 4096 * 4;
  bf16_t* vg    = (bf16_t*)p; p += (size_t)8192 * 8192 * 2;
  bf16_t* y     = (bf16_t*)p; p += (size_t)8192 * 4096 * 2;
  // vg (134MB) is dead after conv_gate: reuse it for split-K fp32 partials
  float* part = (float*)vg;  // 2 * 8192 * 1024 * 4 = 67MB <= 134MB

  cast_f32_to_bf16<<<8192, 256, 0, stream>>>(x, x_bf, 8192 * 1024);
  cast_f32_to_bf16<<<8192, 256, 0, stream>>>(w_in, wi_bf, 8192 * 1024);
  cast_f32_to_bf16<<<4096, 256, 0, stream>>>(w_out, wo_bf, 4096 * 1024);
  transpose_w<<<2032, 256, 0, stream>>>(w_dw, wt);

  // vg[8192,8192] = x[8192,1024] @ w_in[8192,1024]^T
  gemm_bt<bf16_t><<<dim3(64, 64), 256, 0, stream>>>(x_bf, wi_bf, vg,
                                                    8192, 8192, 1024);
  // y = silu(causal_dwconv(v)+b) * silu(g)
  conv_gate<<<dim3(64, 64), 256, 0, stream>>>(vg, wt, b_dw, y);
  // out[8192,1024] = y[8192,4096] @ w_out[1024,4096]^T  (split-K=2)
  gemm_bt_split<<<dim3(8, 64, 2), 256, 0, stream>>>(y, wo_bf, part,
                                                    8192, 1024, 4096, 2048);
  reduce2<<<8192, 256, 0, stream>>>(part, out, 8192 * 1024);
}

// Round 3
// 501.584 us; speedup vs baseline: 1.1949x; 1.1949x over previous
//
#include <hip/hip_runtime.h>
#include <hip/hip_bf16.h>
#include <cstdint>
#include <cstddef>

typedef __bf16 bf16_t;
typedef __attribute__((ext_vector_type(8))) __bf16 bf16x8;
typedef __attribute__((ext_vector_type(4))) __bf16 bf16x4;
typedef __attribute__((ext_vector_type(4))) float floatx4;

// ---------------------------------------------------------------- helpers
__device__ __forceinline__ void async_copy_16B(const void* g, void* l) {
  __builtin_amdgcn_global_load_lds(
      (const __attribute__((address_space(1))) void*)g,
      (__attribute__((address_space(3))) void*)l, 16, 0, 0);
}

// ---------------------------------------------------------------- prep
// Fused: cast x (2.097M float4), cast w_in (2.097M), cast w_out (1.049M),
// transpose w_dw [4096][127] -> wt [127][4096] (520192 scalars).
__global__ __launch_bounds__(256) void prep(
    const float* __restrict__ x, const float* __restrict__ w_in,
    const float* __restrict__ w_out, const float* __restrict__ w_dw,
    bf16_t* __restrict__ x_bf, bf16_t* __restrict__ wi_bf,
    bf16_t* __restrict__ wo_bf, float* __restrict__ wt) {
  const int tid = blockIdx.x * 256 + threadIdx.x;
  if (tid < 5242880) {
    const float* src;
    bf16_t* dst;
    int off;
    if (tid < 2097152) {
      src = x; dst = x_bf; off = tid;
    } else if (tid < 4194304) {
      src = w_in; dst = wi_bf; off = tid - 2097152;
    } else {
      src = w_out; dst = wo_bf; off = tid - 4194304;
    }
    const float4 v = *(const float4*)(src + (size_t)off * 4);
    bf16x4 o;
    o.x = (bf16_t)v.x; o.y = (bf16_t)v.y; o.z = (bf16_t)v.z; o.w = (bf16_t)v.w;
    *(bf16x4*)(dst + (size_t)off * 4) = o;
  } else {
    const int idx = tid - 5242880;
    if (idx < 127 * 4096) {
      const int j = idx >> 12;
      const int c = idx & 4095;
      wt[idx] = w_dw[c * 127 + j];
    }
  }
}

// ---------------------------------------------------------------- GEMM (NT)
// C[M,N] = A[M,K] * B[N,K]^T ; A,B bf16 row-major, C = OutT row-major.
// BM=128 rows, BN_ in {128,64}, BK=64 as two 32-col LDS panels (each panel
// keeps the conflict-free ds_read_b128 layout: 16 rows x 64B = contiguous 1KB
// per wave-read). 32 (BN_=128) or 16 (BN_=64) MFMAs per barrier-pair.
template <int BN_, typename OutT>
__global__ __launch_bounds__(256) void gemm_bt64(
    const bf16_t* __restrict__ A, const bf16_t* __restrict__ B,
    OutT* __restrict__ C, int M, int N, int K) {
  constexpr int BM_ = 128;
  constexpr int FI = (BN_ == 128) ? 4 : 2;  // 16-row frags per wave
  constexpr int FJ = 4;                     // 16-col frags per wave
  constexpr int ACH = BM_ * 8;              // A 16B-chunks per K-tile
  constexpr int CH = (BM_ + BN_) * 8;       // total chunks per K-tile
  constexpr int CPT = CH / 256;             // chunks per thread

  __shared__ bf16_t smem[(BM_ + BN_) * 64];
  bf16_t* const As0 = smem;
  bf16_t* const As1 = smem + BM_ * 32;
  bf16_t* const Bs0 = smem + BM_ * 64;
  bf16_t* const Bs1 = smem + BM_ * 64 + BN_ * 32;

  const int t = threadIdx.x;
  const int lane = t & 63;
  const int wave = t >> 6;
  const int m0 = blockIdx.y * BM_;
  const int n0 = blockIdx.x * BN_;
  const int wr = (BN_ == 128) ? (wave >> 1) * 64 : wave * 32;
  const int wc = (BN_ == 128) ? (wave & 1) * 64 : 0;
  const int fr = lane & 15;
  const int fk = (lane >> 4) * 8;

  floatx4 acc[FI][FJ] = {};

  const int kTiles = K / 64;
  for (int kt = 0; kt < kTiles; ++kt) {
    const int k0 = kt * 64;
    __syncthreads();
#pragma unroll
    for (int it = 0; it < CPT; ++it) {
      const int p = it * 256 + t;
      const bf16_t* gsrc;
      if (p < BM_ * 4) {
        const int row = p >> 2, kc = (p & 3) * 8;
        gsrc = A + (size_t)(m0 + row) * K + k0 + kc;
      } else if (p < ACH) {
        const int q = p - BM_ * 4;
        const int row = q >> 2, kc = 32 + (q & 3) * 8;
        gsrc = A + (size_t)(m0 + row) * K + k0 + kc;
      } else if (p < ACH + BN_ * 4) {
        const int q = p - ACH;
        const int row = q >> 2, kc = (q & 3) * 8;
        gsrc = B + (size_t)(n0 + row) * K + k0 + kc;
      } else {
        const int q = p - ACH - BN_ * 4;
        const int row = q >> 2, kc = 32 + (q & 3) * 8;
        gsrc = B + (size_t)(n0 + row) * K + k0 + kc;
      }
      async_copy_16B(gsrc, smem + p * 8);
    }
    __syncthreads();

    bf16x8 af[FI][2], bfr[FJ][2];
#pragma unroll
    for (int i = 0; i < FI; ++i) {
      const int r = (wr + i * 16 + fr) * 32 + fk;
      af[i][0] = *(const bf16x8*)(As0 + r);
      af[i][1] = *(const bf16x8*)(As1 + r);
    }
#pragma unroll
    for (int j = 0; j < FJ; ++j) {
      const int r = (wc + j * 16 + fr) * 32 + fk;
      bfr[j][0] = *(const bf16x8*)(Bs0 + r);
      bfr[j][1] = *(const bf16x8*)(Bs1 + r);
    }
#pragma unroll
    for (int h = 0; h < 2; ++h)
#pragma unroll
      for (int i = 0; i < FI; ++i)
#pragma unroll
        for (int j = 0; j < FJ; ++j)
          acc[i][j] = __builtin_amdgcn_mfma_f32_16x16x32_bf16(
              af[i][h], bfr[j][h], acc[i][j], 0, 0, 0);
  }

  // C/D layout: col = lane&15, row = (lane>>4)*4 + reg
  const int cr = (lane >> 4) * 4;
  const int cc = lane & 15;
#pragma unroll
  for (int i = 0; i < FI; ++i)
#pragma unroll
    for (int j = 0; j < FJ; ++j)
#pragma unroll
      for (int r = 0; r < 4; ++r) {
        const int row = m0 + wr + i * 16 + cr + r;
        const int col = n0 + wc + j * 16 + cc;
        C[(size_t)row * N + col] = (OutT)acc[i][j][r];
      }
}

// ---------------------------------------------------------------- conv+gate
// vg: [8192][8192] bf16 (v = cols 0..4095, g = cols 4096..8191)
// wt: [127][4096] fp32 transposed filters ; y: [8192][4096] bf16
// Block: 64 channels x 128 l-outputs; 4 waves x 32 l's each, lane=channel.
#define CONV_L 128
#define CROWS 254  // 128 + 126 history rows

__global__ __launch_bounds__(256) void conv_gate(
    const bf16_t* __restrict__ vg, const float* __restrict__ wt,
    const float* __restrict__ b_dw, bf16_t* __restrict__ y) {
  __shared__ bf16_t vt[CROWS * 64];
  const int t = threadIdx.x;
  const int lane = t & 63;
  const int wave = t >> 6;
  const int c0 = blockIdx.x * 64;
  const int lt = blockIdx.y & 31;   // 4096/128 = 32 l-tiles
  const int b = blockIdx.y >> 5;
  const int l0 = lt * CONV_L;

  // stage v tile rows [l0-126, l0+127] x 64 channels (zeros for l<0)
  for (int chunk = t; chunk < CROWS * 8; chunk += 256) {
    const int row = chunk >> 3;
    const int cc = (chunk & 7) * 8;
    const int l = l0 - 126 + row;
    uint4* dst = (uint4*)(vt + row * 64 + cc);
    if (l < 0) {
      *dst = make_uint4(0u, 0u, 0u, 0u);
    } else {
      *dst = *(const uint4*)(vg + (size_t)(b * 4096 + l) * 8192 + c0 + cc);
    }
  }
  __syncthreads();

  const int c = c0 + lane;
  const int r0 = wave * 32;  // tile row of v[lb-126]
  const float bias = b_dw[c];
  float acc[32], win[32];
#pragma unroll
  for (int i = 0; i < 32; ++i) acc[i] = bias;
#pragma unroll
  for (int i = 0; i < 32; ++i) win[i] = (float)vt[(r0 + i) * 64 + lane];

  const float* wcp = wt + c;
  // invariant: at start of tap j, win[(j+i)&31] == v[r0+j+i], i in [0,32)
#pragma unroll 1
  for (int jo = 0; jo < 96; jo += 32) {
#pragma unroll
    for (int ji = 0; ji < 32; ++ji) {
      const int j = jo + ji;
      const float wj = wcp[(size_t)j * 4096];
#pragma unroll
      for (int i = 0; i < 32; ++i) acc[i] += wj * win[(ji + i) & 31];
      win[ji] = (float)vt[(r0 + 32 + j) * 64 + lane];
    }
  }
#pragma unroll
  for (int ji = 0; ji < 31; ++ji) {  // tail taps j = 96..126
    const int j = 96 + ji;
    const float wj = wcp[(size_t)j * 4096];
#pragma unroll
    for (int i = 0; i < 32; ++i) acc[i] += wj * win[(ji + i) & 31];
    if (ji < 30) win[ji] = (float)vt[(r0 + 32 + j) * 64 + lane];
  }

  const int lb = l0 + r0;
  const bf16_t* gp = vg + (size_t)(b * 4096 + lb) * 8192 + 4096 + c;
  bf16_t* yp = y + (size_t)(b * 4096 + lb) * 4096 + c;
#pragma unroll
  for (int i = 0; i < 32; ++i) {
    const float gv = (float)gp[(size_t)i * 8192];
    const float v = acc[i];
    const float sv = v / (1.f + __expf(-v));
    const float sg = gv / (1.f + __expf(-gv));
    yp[(size_t)i * 4096] = (bf16_t)(sv * sg);
  }
}

// ---------------------------------------------------------------- launch
extern "C" void kernel_launch(void* const* d_in, const int* in_sizes, int n_in,
                              void* d_out, int out_size, void* d_ws,
                              size_t ws_size, hipStream_t stream) {
  const float* x     = (const float*)d_in[0];  // [2,4096,1024]
  const float* w_in  = (const float*)d_in[1];  // [8192,1024]
  const float* w_dw  = (const float*)d_in[2];  // [4096,127]
  const float* b_dw  = (const float*)d_in[3];  // [4096]
  const float* w_out = (const float*)d_in[4];  // [1024,4096]
  float* out = (float*)d_out;                  // [2,4096,1024]

  char* p = (char*)d_ws;
  bf16_t* x_bf  = (bf16_t*)p; p += (size_t)8192 * 1024 * 2;
  bf16_t* wi_bf = (bf16_t*)p; p += (size_t)8192 * 1024 * 2;
  bf16_t* wo_bf = (bf16_t*)p; p += (size_t)1024 * 4096 * 2;
  float*  wt    = (float*)p;  p += (size_t)127 * 4096 * 4;
  bf16_t* vg    = (bf16_t*)p; p += (size_t)8192 * 8192 * 2;
  bf16_t* y     = (bf16_t*)p; p += (size_t)8192 * 4096 * 2;

  // fused casts + filter transpose
  prep<<<22512, 256, 0, stream>>>(x, w_in, w_out, w_dw, x_bf, wi_bf, wo_bf, wt);

  // vg[8192,8192] = x[8192,1024] @ w_in[8192,1024]^T
  gemm_bt64<128, bf16_t><<<dim3(64, 64), 256, 0, stream>>>(x_bf, wi_bf, vg,
                                                           8192, 8192, 1024);
  // y = silu(causal_dwconv(v)+b) * silu(g)
  conv_gate<<<dim3(64, 64), 256, 0, stream>>>(vg, wt, b_dw, y);
  // out[8192,1024] = y[8192,4096] @ w_out[1024,4096]^T (128x64 tiles, 4/CU)
  gemm_bt64<64, float><<<dim3(16, 64), 256, 0, stream>>>(y, wo_bf, out,
                                                         8192, 1024, 4096);
}